// Round 8
// baseline (1416.457 us; speedup 1.0000x reference)
//
#include <hip/hip_runtime.h>

typedef float f32x4 __attribute__((ext_vector_type(4)));
typedef short s16x8 __attribute__((ext_vector_type(8)));
typedef unsigned uint4v __attribute__((ext_vector_type(4)));

#define HH   768
#define SS   256
#define GR   8     // row groups (16 rows each); g = blockIdx & 7
#define GP   24    // col blocks per group; p = blockIdx >> 3
#define NROW 128
#define LDP  776   // LDS row pitch (shorts)

__device__ __forceinline__ unsigned short f2bf(float f) {
  unsigned int u = __float_as_uint(f);
  u += 0x7FFFu + ((u >> 16) & 1u);          // RTNE
  return (unsigned short)(u >> 16);
}
__device__ __forceinline__ float bf2f(unsigned short s) {
  return __uint_as_float(((unsigned int)s) << 16);
}
__device__ __forceinline__ float sigm(float v) { return 1.0f / (1.0f + __expf(-v)); }
__device__ __forceinline__ float tanhf_(float v) {
  return 1.0f - 2.0f / (__expf(2.0f * v) + 1.0f);
}

// 192 blocks x 256 threads, plain launch (all co-resident, 1 block/CU).
// Static roles: g = blockIdx&7 (rows [16g,16g+16)), p = blockIdx>>3 (hidden
// cols [32p,32p+32)); gate cols permuted col = hcol*4 + gate.
//
// R6-proven: vote (all 24 group members share one XCC_ID) gates an XCD-local
// h data path (plain write-through stores -> XCD L2; plain vector loads with
// 3 buffer parities => ~144KB L1 reuse distance => never stale L1).
// R8 sync (fast mode): per-block sequence flags in the XCD L2.
//   arrive: one plain write-through u32 store (flag = t+2) after drained
//           __syncthreads.
//   wait:   wave0 lanes 0..23 poll with fetch_add(flag, zpoll) where zpoll is
//           a RUNTIME zero (loaded from memset'd workspace) — defeats LLVM's
//           idempotent-atomicrmw->load folding (the R4/R5/R7 hang cause: the
//           folded workgroup-scope load hit stale L1 and spun forever). The
//           surviving RMW executes at the local L2 => always fresh.
// Max skew = 1 step => 3-parity WAR reasoning unchanged.
// Slow fallback: R3 agent-scope counter barrier, verbatim.
__global__ void __launch_bounds__(256, 1) lstm_persistent(
    const float* __restrict__ xin, const float* __restrict__ h0,
    const float* __restrict__ c0,
    const float* __restrict__ Wi, const float* __restrict__ bi,
    const float* __restrict__ Wf, const float* __restrict__ bfv,
    const float* __restrict__ Wc, const float* __restrict__ bc,
    const float* __restrict__ Wo, const float* __restrict__ bo,
    const float* __restrict__ Wout, const float* __restrict__ bout,
    float* __restrict__ out,
    unsigned short* __restrict__ hhi0, unsigned short* __restrict__ hhi1,
    unsigned short* __restrict__ hhi2,
    unsigned short* __restrict__ hlo0, unsigned short* __restrict__ hlo1,
    unsigned short* __restrict__ hlo2,
    unsigned* __restrict__ bar)
{
  const int tid = threadIdx.x, wave = tid >> 6, lane = tid & 63;
  const int l15 = lane & 15, quad = lane >> 4;
  const int g = blockIdx.x & 7, p = blockIdx.x >> 3;
  const int row_base = g * 16, hcol_base = p * 32;

  __shared__ __align__(16) unsigned short lds_hi[16 * LDP];
  __shared__ __align__(16) unsigned short lds_lo[16 * LDP];
  __shared__ __align__(16) float gate_lds[16][132];
  __shared__ float c_lds[16][33];
  __shared__ float x_lds[16];
  __shared__ int s_fast;

  unsigned* ctr   = bar + g * 64;            // slow-path barrier (256B-spaced)
  unsigned* rdy   = bar + 512 + g * 16;      // rendezvous counter
  unsigned* ids   = bar + 640 + g * 32;      // 24 published XCC_IDs
  unsigned* flags = bar + 1024 + g * 384;    // 24 flags, 64B-spaced

  // Runtime zero for poll RMWs (bar[896] is memset to 0, never written).
  const unsigned zpoll = __hip_atomic_load(bar + 896, __ATOMIC_RELAXED,
                                           __HIP_MEMORY_SCOPE_AGENT);

  // ---- one-time vote (tid0), overlapped with weight gather on other lanes --
  if (tid == 0) {
    // HW_REG_XCC_ID: id 20, offset 0, width 4 [measured: learn_hip m09]
    const unsigned my = (__builtin_amdgcn_s_getreg(20 | (3 << 11)) & 15u) + 1u;
    __hip_atomic_store(ids + p, my, __ATOMIC_RELAXED, __HIP_MEMORY_SCOPE_AGENT);
    __hip_atomic_fetch_add(rdy, 1u, __ATOMIC_RELEASE, __HIP_MEMORY_SCOPE_AGENT);
    while (__hip_atomic_load(rdy, __ATOMIC_ACQUIRE, __HIP_MEMORY_SCOPE_AGENT)
           < (unsigned)GP)
      __builtin_amdgcn_s_sleep(8);
    int ok = 1;
    for (int q = 0; q < GP; ++q)
      ok &= (__hip_atomic_load(ids + q, __ATOMIC_RELAXED,
                               __HIP_MEMORY_SCOPE_AGENT) == my);
    s_fast = ok;                             // same verdict in all 24 blocks
  }

  // ---- one-time: weights -> bf16 hi/lo B-fragments (n=lane&15, k=quad*8+j) --
  s16x8 Bhi[24][2], Blo[24][2];
  float bv[2], w0v[2];
#pragma unroll
  for (int n = 0; n < 2; ++n) {
    const int col = p * 128 + wave * 32 + n * 16 + l15;   // permuted gate col
    const int gg = col & 3, hc = col >> 2;
    const float* W  = (gg == 0) ? Wi : (gg == 1) ? Wf : (gg == 2) ? Wc : Wo;
    const float* bb = (gg == 0) ? bi : (gg == 1) ? bfv : (gg == 2) ? bc : bo;
    bv[n]  = bb[hc];
    w0v[n] = W[hc];                          // W row 0 = x weight (exact fp32)
#pragma unroll
    for (int kt = 0; kt < 24; ++kt) {
      s16x8 vh, vl;
#pragma unroll
      for (int j = 0; j < 8; ++j) {
        const int k = kt * 32 + quad * 8 + j;
        const float w = W[(1 + k) * HH + hc];
        const unsigned short hi = f2bf(w);
        vh[j] = (short)hi;
        vl[j] = (short)f2bf(w - bf2f(hi));
      }
      Bhi[kt][n] = vh; Blo[kt][n] = vl;
    }
  }

  // ---- init: c->LDS; h0 -> parity-0 buffers ----
  {
    const int lr = tid >> 4, lc = (tid & 15) * 2;
    const int gidx = (row_base + lr) * HH + hcol_base + lc;
    const float ha = h0[gidx], hb = h0[gidx + 1];
    c_lds[lr][lc]     = c0[gidx];
    c_lds[lr][lc + 1] = c0[gidx + 1];
    const unsigned short ha_hi = f2bf(ha), hb_hi = f2bf(hb);
    const unsigned short ha_lo = f2bf(ha - bf2f(ha_hi));
    const unsigned short hb_lo = f2bf(hb - bf2f(hb_hi));
    __hip_atomic_store((unsigned*)hhi0 + (gidx >> 1),
                       (unsigned)ha_hi | ((unsigned)hb_hi << 16),
                       __ATOMIC_RELAXED, __HIP_MEMORY_SCOPE_AGENT);
    __hip_atomic_store((unsigned*)hlo0 + (gidx >> 1),
                       (unsigned)ha_lo | ((unsigned)hb_lo << 16),
                       __ATOMIC_RELAXED, __HIP_MEMORY_SCOPE_AGENT);
    if (tid < 16) {
      const int row = row_base + tid;
      x_lds[tid] = xin[(row >> 1) * (SS * 2) + (row & 1)];   // t = 0
    }
  }
  __syncthreads();                           // s_fast + LDS init visible
  const bool fast = (s_fast != 0);
  unsigned bars = 0;

  // Slow-path barrier (R3-proven, agent scope).
  auto gbar = [&]() {
    __builtin_amdgcn_s_waitcnt(0);
    __syncthreads();
    if (tid == 0) {
      ++bars;
      __hip_atomic_fetch_add(ctr, 1u, __ATOMIC_RELAXED, __HIP_MEMORY_SCOPE_AGENT);
      const unsigned want = (unsigned)GP * bars;
      while (__hip_atomic_load(ctr, __ATOMIC_RELAXED, __HIP_MEMORY_SCOPE_AGENT) < want)
        __builtin_amdgcn_s_sleep(1);
    }
    __syncthreads();
  };

  // Fast-path wait: all 24 peer flags >= want. zpoll (runtime 0) keeps the
  // RMW un-foldable => executes at the XCD-local L2, always fresh.
  auto fast_wait = [&](unsigned want) {
    if (wave == 0 && lane < GP) {
      unsigned* f = flags + lane * 16;
      while (__hip_atomic_fetch_add(f, zpoll, __ATOMIC_RELAXED,
                                    __HIP_MEMORY_SCOPE_WORKGROUP) < want)
        __builtin_amdgcn_s_sleep(1);
    }
    __syncthreads();
  };
  // Fast-path arrive: plain write-through store (all waves pre-drained).
  auto fast_arrive = [&](unsigned val) {
    if (tid == 0)
      __hip_atomic_store(flags + p * 16, val, __ATOMIC_RELAXED,
                         __HIP_MEMORY_SCOPE_WORKGROUP);
  };

  // publish h0/c0
  if (fast) {
    __builtin_amdgcn_s_waitcnt(0);
    __syncthreads();                         // all init stores drained
    fast_arrive(1u);                         // flag=1 <=> h[0] published
  } else {
    gbar();
  }

  const unsigned short* hbhi[3] = {hhi0, hhi1, hhi2};
  const unsigned short* hblo[3] = {hlo0, hlo1, hlo2};
  unsigned short* wbhi[3] = {hhi0, hhi1, hhi2};
  unsigned short* wblo[3] = {hlo0, hlo1, hlo2};

  const int frag_off = l15 * LDP + quad * 8; // A-frag LDS offset (shorts)
  int cur = 0;

  for (int t = 0; t < SS; ++t) {
    const int nxt = (cur == 2) ? 0 : cur + 1;
    const unsigned short* rhi = hbhi[cur];
    const unsigned short* rlo = hblo[cur];
    unsigned short* whi = wbhi[nxt];
    unsigned short* wlo = wblo[nxt];

    if (fast) fast_wait((unsigned)t + 1u);   // all peers published h[t]

    // ---- stage group h-slice (16x768 hi+lo) into LDS ----
    if (fast) {                              // plain 16B loads from XCD L2
      const uint4v* rh = (const uint4v*)(rhi + row_base * HH);
      const uint4v* rl = (const uint4v*)(rlo + row_base * HH);
#pragma unroll
      for (int b = 0; b < 2; ++b) {
        uint4v hv[3], lv[3];
#pragma unroll
        for (int j = 0; j < 3; ++j) {
          const int gi = (b * 3 + j) * 256 + tid;   // u128 idx in [0,1536)
          hv[j] = rh[gi]; lv[j] = rl[gi];
        }
#pragma unroll
        for (int j = 0; j < 3; ++j) {
          const int gi = (b * 3 + j) * 256 + tid;
          const int rr = gi / 96, cc = (gi - rr * 96) * 8;
          *(uint4v*)&lds_hi[rr * LDP + cc] = hv[j];
          *(uint4v*)&lds_lo[rr * LDP + cc] = lv[j];
        }
      }
    } else {                                 // agent-scope (MALL) loads
      const int u64_base = row_base * 192;
#pragma unroll
      for (int i = 0; i < 12; ++i) {
        const int gi = i * 256 + tid;        // u64 idx in [0,3072)
        const int rr = gi / 192, cc = (gi - rr * 192) * 4;
        const unsigned long long vh = __hip_atomic_load(
            (unsigned long long*)rhi + u64_base + gi, __ATOMIC_RELAXED, __HIP_MEMORY_SCOPE_AGENT);
        const unsigned long long vl = __hip_atomic_load(
            (unsigned long long*)rlo + u64_base + gi, __ATOMIC_RELAXED, __HIP_MEMORY_SCOPE_AGENT);
        *(unsigned long long*)&lds_hi[rr * LDP + cc] = vh;
        *(unsigned long long*)&lds_lo[rr * LDP + cc] = vl;
      }
    }
    __syncthreads();

    // ---- GEMM: 3-product bf16 hi/lo MFMA (C/D: col=lane&15,row=quad*4+reg) --
    f32x4 ahh[2], ahl[2], alh[2];
#pragma unroll
    for (int n = 0; n < 2; ++n)
#pragma unroll
      for (int reg = 0; reg < 4; ++reg) {
        ahh[n][reg] = bv[n] + x_lds[quad * 4 + reg] * w0v[n];
        ahl[n][reg] = 0.0f; alh[n][reg] = 0.0f;
      }
#pragma unroll
    for (int kt = 0; kt < 24; ++kt) {
      const s16x8 ah = *(const s16x8*)&lds_hi[frag_off + kt * 32];
      const s16x8 al = *(const s16x8*)&lds_lo[frag_off + kt * 32];
#pragma unroll
      for (int n = 0; n < 2; ++n) {
        ahh[n] = __builtin_amdgcn_mfma_f32_16x16x32_bf16(ah, Bhi[kt][n], ahh[n], 0, 0, 0);
        ahl[n] = __builtin_amdgcn_mfma_f32_16x16x32_bf16(ah, Blo[kt][n], ahl[n], 0, 0, 0);
        alh[n] = __builtin_amdgcn_mfma_f32_16x16x32_bf16(al, Bhi[kt][n], alh[n], 0, 0, 0);
      }
    }
    __syncthreads();                         // lds reuse + gate_lds WAR

#pragma unroll
    for (int n = 0; n < 2; ++n)
#pragma unroll
      for (int reg = 0; reg < 4; ++reg)
        gate_lds[quad * 4 + reg][wave * 32 + n * 16 + l15] =
            (ahh[n][reg] + ahl[n][reg]) + alh[n][reg];
    __syncthreads();

    // ---- elementwise; h store via voted protocol ----
    {
      const int lr = tid >> 4, lc = (tid & 15) * 2;
      const f32x4 g0 = *(const f32x4*)&gate_lds[lr][lc * 4];     // i,f,chat,o
      const f32x4 g1 = *(const f32x4*)&gate_lds[lr][lc * 4 + 4];
      float ca = c_lds[lr][lc], cb = c_lds[lr][lc + 1];
      ca = sigm(g0[1]) * ca + sigm(g0[0]) * tanhf_(g0[2]);
      cb = sigm(g1[1]) * cb + sigm(g1[0]) * tanhf_(g1[2]);
      const float ha = g0[3] * tanhf_(ca);   // no sigmoid on o-gate (ref)
      const float hb = g1[3] * tanhf_(cb);
      c_lds[lr][lc] = ca; c_lds[lr][lc + 1] = cb;
      const int gidx = (row_base + lr) * HH + hcol_base + lc;
      const unsigned short ha_hi = f2bf(ha), hb_hi = f2bf(hb);
      const unsigned short ha_lo = f2bf(ha - bf2f(ha_hi));
      const unsigned short hb_lo = f2bf(hb - bf2f(hb_hi));
      const unsigned ph = (unsigned)ha_hi | ((unsigned)hb_hi << 16);
      const unsigned pl = (unsigned)ha_lo | ((unsigned)hb_lo << 16);
      if (fast) {                            // write-through L1 -> XCD L2
        ((unsigned*)whi)[gidx >> 1] = ph;
        ((unsigned*)wlo)[gidx >> 1] = pl;
      } else {
        __hip_atomic_store((unsigned*)whi + (gidx >> 1), ph, __ATOMIC_RELAXED, __HIP_MEMORY_SCOPE_AGENT);
        __hip_atomic_store((unsigned*)wlo + (gidx >> 1), pl, __ATOMIC_RELAXED, __HIP_MEMORY_SCOPE_AGENT);
      }
      if (tid < 16 && t + 1 < SS) {
        const int row = row_base + tid;
        x_lds[tid] = xin[(row >> 1) * (SS * 2) + (t + 1) * 2 + (row & 1)];
      }
    }

    if (fast) {
      __builtin_amdgcn_s_waitcnt(0);
      __syncthreads();                       // all h[t+1] stores drained
      fast_arrive((unsigned)t + 2u);         // publish h[t+1]
    } else {
      gbar();
    }
    cur = nxt;
  }

  // ---- output projection: final h in parity cur = 256%3 = 1 ----
  if (p == 0) {
    if (fast) fast_wait((unsigned)SS + 1u);  // all peers published h[SS]
    const unsigned short* fhi = hbhi[cur];
    const unsigned short* flo = hblo[cur];
    const int rloc = tid >> 4, s = tid & 15;
    const int row = row_base + rloc;
    float sum = 0.0f;
#pragma unroll
    for (int i = 0; i < 12; ++i) {
      const int u = row * 192 + s * 12 + i;  // u64 idx; k0 = s*48 + i*4
      unsigned long long vh, vl;
      if (fast) {                            // fresh in this XCD's L2
        vh = *((const unsigned long long*)fhi + u);
        vl = *((const unsigned long long*)flo + u);
      } else {
        vh = __hip_atomic_load((unsigned long long*)fhi + u, __ATOMIC_RELAXED, __HIP_MEMORY_SCOPE_AGENT);
        vl = __hip_atomic_load((unsigned long long*)flo + u, __ATOMIC_RELAXED, __HIP_MEMORY_SCOPE_AGENT);
      }
#pragma unroll
      for (int j = 0; j < 4; ++j) {
        const float h = bf2f((unsigned short)(vh >> (16 * j))) +
                        bf2f((unsigned short)(vl >> (16 * j)));
        sum += h * Wout[s * 48 + i * 4 + j];
      }
    }
#pragma unroll
    for (int off = 8; off; off >>= 1) sum += __shfl_down(sum, off, 16);
    if (s == 0) out[row] = sum + bout[0];
  }
}

extern "C" void kernel_launch(void* const* d_in, const int* in_sizes, int n_in,
                              void* d_out, int out_size, void* d_ws, size_t ws_size,
                              hipStream_t stream) {
  const float* xin  = (const float*)d_in[0];
  const float* h0   = (const float*)d_in[1];
  const float* c0   = (const float*)d_in[2];
  const float* Wi   = (const float*)d_in[3];
  const float* bi   = (const float*)d_in[4];
  const float* Wf   = (const float*)d_in[5];
  const float* bfv  = (const float*)d_in[6];
  const float* Wc   = (const float*)d_in[7];
  const float* bc   = (const float*)d_in[8];
  const float* Wo   = (const float*)d_in[9];
  const float* bo   = (const float*)d_in[10];
  const float* Wout = (const float*)d_in[11];
  const float* bout = (const float*)d_in[12];
  float* out = (float*)d_out;

  char* ws = (char*)d_ws;
  const size_t HB = (size_t)NROW * HH * sizeof(unsigned short);  // 196608
  unsigned short* hhi0 = (unsigned short*)(ws);
  unsigned short* hhi1 = (unsigned short*)(ws + HB);
  unsigned short* hhi2 = (unsigned short*)(ws + 2 * HB);
  unsigned short* hlo0 = (unsigned short*)(ws + 3 * HB);
  unsigned short* hlo1 = (unsigned short*)(ws + 4 * HB);
  unsigned short* hlo2 = (unsigned short*)(ws + 5 * HB);
  unsigned*       bar  = (unsigned*)(ws + 6 * HB);

  hipMemsetAsync(bar, 0, 16384, stream);   // zero barrier/rendezvous/flags

  (void)in_sizes; (void)n_in; (void)out_size; (void)ws_size;
  hipLaunchKernelGGL(lstm_persistent, dim3(GR * GP), dim3(256), 0, stream,
                     xin, h0, c0, Wi, bi, Wf, bfv, Wc, bc, Wo, bo,
                     Wout, bout, out, hhi0, hhi1, hhi2, hlo0, hlo1, hlo2, bar);
}

// Round 9
// 972.636 us; speedup vs baseline: 1.4563x; 1.4563x over previous
//
#include <hip/hip_runtime.h>

typedef float f32x4 __attribute__((ext_vector_type(4)));
typedef short s16x8 __attribute__((ext_vector_type(8)));
typedef unsigned uint4v __attribute__((ext_vector_type(4)));

#define HH   768
#define SS   256
#define GR   8     // row groups (16 rows each); g = blockIdx & 7
#define GP   24    // col blocks per group; p = blockIdx >> 3
#define NROW 128
#define LDP  776   // LDS row pitch (shorts); 1552B = 16B-aligned rows
#define PP   68    // partials row pitch (floats)

__device__ __forceinline__ unsigned short f2bf(float f) {
  unsigned int u = __float_as_uint(f);
  u += 0x7FFFu + ((u >> 16) & 1u);          // RTNE
  return (unsigned short)(u >> 16);
}
__device__ __forceinline__ float bf2f(unsigned short s) {
  return __uint_as_float(((unsigned int)s) << 16);
}
__device__ __forceinline__ float sigm(float v) { return 1.0f / (1.0f + __expf(-v)); }
__device__ __forceinline__ float tanhf_(float v) {
  return 1.0f - 2.0f / (__expf(2.0f * v) + 1.0f);
}

// 192 blocks x 512 threads (8 waves, 2/SIMD via launch_bounds(512,2)).
// Static roles: g = blockIdx&7 (rows [16g,16g+16)), p = blockIdx>>3 (hidden
// cols [32p,32p+32)); gate cols permuted col = hcol*4 + gate.
// Wave w: colh = w&1 (64-gate-col half), ks = w>>1 (6-kt slice of K).
//   => B-frags 6kt x 4n x hi/lo = 192 VGPR; merged f32 acc (hh+hl+lh chained
//   into one accumulator) = 16 VGPR; A-slice read by only 2 waves => LDS
//   fragment traffic 96KB/step (was 192KB at 4 waves full-K).
// Partials: LDS [colh][ks][16][PP], reduced over ks by 512 threads (1 cell
// each); bias + x*w0 added at reduction from LDS tables.
// Transport/sync: R6-proven verbatim — XCC_ID vote gating write-through
// stores + plain loads in the XCD L2 (3 parities defeat stale L1), agent-
// scope counter barrier (R8's parallel flag polls REGRESSED; reverted).
__global__ void __launch_bounds__(512, 2) lstm_persistent(
    const float* __restrict__ xin, const float* __restrict__ h0,
    const float* __restrict__ c0,
    const float* __restrict__ Wi, const float* __restrict__ bi,
    const float* __restrict__ Wf, const float* __restrict__ bfv,
    const float* __restrict__ Wc, const float* __restrict__ bc,
    const float* __restrict__ Wo, const float* __restrict__ bo,
    const float* __restrict__ Wout, const float* __restrict__ bout,
    float* __restrict__ out,
    unsigned short* __restrict__ hhi0, unsigned short* __restrict__ hhi1,
    unsigned short* __restrict__ hhi2,
    unsigned short* __restrict__ hlo0, unsigned short* __restrict__ hlo1,
    unsigned short* __restrict__ hlo2,
    unsigned* __restrict__ bar)
{
  const int tid = threadIdx.x, wave = tid >> 6, lane = tid & 63;
  const int l15 = lane & 15, quad = lane >> 4;
  const int g = blockIdx.x & 7, p = blockIdx.x >> 3;
  const int row_base = g * 16, hcol_base = p * 32;
  const int colh = wave & 1, ks = wave >> 1;   // col-half / kt-slice

  __shared__ __align__(16) unsigned short lds_hi[16 * LDP];
  __shared__ __align__(16) unsigned short lds_lo[16 * LDP];
  __shared__ __align__(16) float part[2][4][16][PP];   // [colh][ks][row][col64]
  __shared__ float bw_b[128], bw_w[128];               // bias / x-weight per col
  __shared__ float c_lds[16][33];
  __shared__ float x_lds[16];
  __shared__ int s_fast;

  unsigned* ctr = bar + g * 64;              // step barrier (256B-spaced)
  unsigned* rdy = bar + 512 + g * 16;        // rendezvous counter
  unsigned* ids = bar + 640 + g * 32;        // 24 published XCC_IDs

  // ---- one-time vote (tid0): all 24 members on one XCD? [R6-proven] ----
  if (tid == 0) {
    const unsigned my = (__builtin_amdgcn_s_getreg(20 | (3 << 11)) & 15u) + 1u;
    __hip_atomic_store(ids + p, my, __ATOMIC_RELAXED, __HIP_MEMORY_SCOPE_AGENT);
    __hip_atomic_fetch_add(rdy, 1u, __ATOMIC_RELEASE, __HIP_MEMORY_SCOPE_AGENT);
    while (__hip_atomic_load(rdy, __ATOMIC_ACQUIRE, __HIP_MEMORY_SCOPE_AGENT)
           < (unsigned)GP)
      __builtin_amdgcn_s_sleep(8);
    int ok = 1;
    for (int q = 0; q < GP; ++q)
      ok &= (__hip_atomic_load(ids + q, __ATOMIC_RELAXED,
                               __HIP_MEMORY_SCOPE_AGENT) == my);
    s_fast = ok;
  }

  // ---- one-time: weights -> bf16 hi/lo B-fragments (n=lane&15, k=quad*8+j) --
  s16x8 Bhi[6][4], Blo[6][4];
#pragma unroll
  for (int n = 0; n < 4; ++n) {
    const int col = p * 128 + colh * 64 + n * 16 + l15;  // permuted gate col
    const int gg = col & 3, hc = col >> 2;
    const float* W = (gg == 0) ? Wi : (gg == 1) ? Wf : (gg == 2) ? Wc : Wo;
#pragma unroll
    for (int ktl = 0; ktl < 6; ++ktl) {
      const int kt = ks * 6 + ktl;
      s16x8 vh, vl;
#pragma unroll
      for (int j = 0; j < 8; ++j) {
        const int k = kt * 32 + quad * 8 + j;
        const float w = W[(1 + k) * HH + hc];
        const unsigned short hi = f2bf(w);
        vh[j] = (short)hi;
        vl[j] = (short)f2bf(w - bf2f(hi));
      }
      Bhi[ktl][n] = vh; Blo[ktl][n] = vl;
    }
  }

  // ---- one-time: bias + x-weight tables -> LDS (per permuted gate col) ----
  if (tid < 128) {
    const int gg = tid & 3;
    const int hc = p * 32 + (tid >> 2);
    const float* W  = (gg == 0) ? Wi : (gg == 1) ? Wf : (gg == 2) ? Wc : Wo;
    const float* bb = (gg == 0) ? bi : (gg == 1) ? bfv : (gg == 2) ? bc : bo;
    bw_b[tid] = bb[hc];
    bw_w[tid] = W[hc];                       // W row 0 = x weight (exact fp32)
  }

  // ---- init: c->LDS; h0 -> parity-0 buffers (agent stores, proto-neutral) --
  if (tid < 256) {
    const int lr = tid >> 4, lc = (tid & 15) * 2;
    const int gidx = (row_base + lr) * HH + hcol_base + lc;
    const float ha = h0[gidx], hb = h0[gidx + 1];
    c_lds[lr][lc]     = c0[gidx];
    c_lds[lr][lc + 1] = c0[gidx + 1];
    const unsigned short ha_hi = f2bf(ha), hb_hi = f2bf(hb);
    const unsigned short ha_lo = f2bf(ha - bf2f(ha_hi));
    const unsigned short hb_lo = f2bf(hb - bf2f(hb_hi));
    __hip_atomic_store((unsigned*)hhi0 + (gidx >> 1),
                       (unsigned)ha_hi | ((unsigned)hb_hi << 16),
                       __ATOMIC_RELAXED, __HIP_MEMORY_SCOPE_AGENT);
    __hip_atomic_store((unsigned*)hlo0 + (gidx >> 1),
                       (unsigned)ha_lo | ((unsigned)hb_lo << 16),
                       __ATOMIC_RELAXED, __HIP_MEMORY_SCOPE_AGENT);
    if (tid < 16) {
      const int row = row_base + tid;
      x_lds[tid] = xin[(row >> 1) * (SS * 2) + (row & 1)];   // t = 0
    }
  }
  __syncthreads();                           // s_fast + LDS init visible
  const bool fast = (s_fast != 0);
  unsigned bars = 0;

  // Agent-scope counter barrier (R3/R6-proven; R8 flag variant regressed).
  auto gbar = [&]() {
    __builtin_amdgcn_s_waitcnt(0);
    __syncthreads();
    if (tid == 0) {
      ++bars;
      __hip_atomic_fetch_add(ctr, 1u, __ATOMIC_RELAXED, __HIP_MEMORY_SCOPE_AGENT);
      const unsigned want = (unsigned)GP * bars;
      while (__hip_atomic_load(ctr, __ATOMIC_RELAXED, __HIP_MEMORY_SCOPE_AGENT) < want)
        __builtin_amdgcn_s_sleep(1);
    }
    __syncthreads();
  };

  gbar();                                    // h0/c0 published

  const unsigned short* hbhi[3] = {hhi0, hhi1, hhi2};
  const unsigned short* hblo[3] = {hlo0, hlo1, hlo2};
  unsigned short* wbhi[3] = {hhi0, hhi1, hhi2};
  unsigned short* wblo[3] = {hlo0, hlo1, hlo2};

  const int frag_off = l15 * LDP + quad * 8; // A-frag LDS offset (shorts)
  const int lr_c = tid >> 5, lc_c = tid & 31;        // elementwise cell
  const int ch_c = lc_c >> 4, c4_c = (lc_c & 15) * 4;
  int cur = 0;

  for (int t = 0; t < SS; ++t) {
    const int nxt = (cur == 2) ? 0 : cur + 1;
    const unsigned short* rhi = hbhi[cur];
    const unsigned short* rlo = hblo[cur];
    unsigned short* whi = wbhi[nxt];
    unsigned short* wlo = wblo[nxt];

    // ---- stage group h-slice (16x768 hi+lo) into LDS ----
    if (fast) {                              // plain 16B loads from XCD L2
      const uint4v* rh = (const uint4v*)(rhi + row_base * HH);
      const uint4v* rl = (const uint4v*)(rlo + row_base * HH);
      uint4v hv[3], lv[3];
#pragma unroll
      for (int i = 0; i < 3; ++i) {
        const int gi = i * 512 + tid;        // u128 idx in [0,1536)
        hv[i] = rh[gi]; lv[i] = rl[gi];
      }
#pragma unroll
      for (int i = 0; i < 3; ++i) {
        const int gi = i * 512 + tid;
        const int rr = gi / 96, cc = (gi - rr * 96) * 8;
        *(uint4v*)&lds_hi[rr * LDP + cc] = hv[i];
        *(uint4v*)&lds_lo[rr * LDP + cc] = lv[i];
      }
    } else {                                 // agent-scope (MALL) loads
      const int u64_base = row_base * 192;
#pragma unroll
      for (int i = 0; i < 6; ++i) {
        const int gi = i * 512 + tid;        // u64 idx in [0,3072)
        const int rr = gi / 192, cc = (gi - rr * 192) * 4;
        const unsigned long long vh = __hip_atomic_load(
            (unsigned long long*)rhi + u64_base + gi, __ATOMIC_RELAXED, __HIP_MEMORY_SCOPE_AGENT);
        const unsigned long long vl = __hip_atomic_load(
            (unsigned long long*)rlo + u64_base + gi, __ATOMIC_RELAXED, __HIP_MEMORY_SCOPE_AGENT);
        *(unsigned long long*)&lds_hi[rr * LDP + cc] = vh;
        *(unsigned long long*)&lds_lo[rr * LDP + cc] = vl;
      }
    }
    __syncthreads();

    // ---- GEMM: wave (colh,ks): 6kt x 4n, merged f32 acc (hh+hl+lh) ----
    f32x4 acc[4] = {{0,0,0,0},{0,0,0,0},{0,0,0,0},{0,0,0,0}};
#pragma unroll
    for (int ktl = 0; ktl < 6; ++ktl) {
      const int kt = ks * 6 + ktl;
      const s16x8 ah = *(const s16x8*)&lds_hi[frag_off + kt * 32];
      const s16x8 al = *(const s16x8*)&lds_lo[frag_off + kt * 32];
#pragma unroll
      for (int n = 0; n < 4; ++n) {
        acc[n] = __builtin_amdgcn_mfma_f32_16x16x32_bf16(ah, Bhi[ktl][n], acc[n], 0, 0, 0);
        acc[n] = __builtin_amdgcn_mfma_f32_16x16x32_bf16(ah, Blo[ktl][n], acc[n], 0, 0, 0);
        acc[n] = __builtin_amdgcn_mfma_f32_16x16x32_bf16(al, Bhi[ktl][n], acc[n], 0, 0, 0);
      }
    }

    // ---- partial write: C/D layout col=l15, row=quad*4+reg ----
#pragma unroll
    for (int n = 0; n < 4; ++n)
#pragma unroll
      for (int reg = 0; reg < 4; ++reg)
        part[colh][ks][quad * 4 + reg][n * 16 + l15] = acc[n][reg];
    __syncthreads();

    // ---- reduce over ks + bias + x*w0; elementwise; h store (1 cell/thr) --
    {
      const f32x4 s0 = *(const f32x4*)&part[ch_c][0][lr_c][c4_c];
      const f32x4 s1 = *(const f32x4*)&part[ch_c][1][lr_c][c4_c];
      const f32x4 s2 = *(const f32x4*)&part[ch_c][2][lr_c][c4_c];
      const f32x4 s3 = *(const f32x4*)&part[ch_c][3][lr_c][c4_c];
      const f32x4 bq = *(const f32x4*)&bw_b[lc_c * 4];
      const f32x4 wq = *(const f32x4*)&bw_w[lc_c * 4];
      const float xv = x_lds[lr_c];
      f32x4 gv = (s0 + s1) + (s2 + s3);
#pragma unroll
      for (int j = 0; j < 4; ++j) gv[j] += bq[j] + xv * wq[j];

      float cc = c_lds[lr_c][lc_c];
      cc = sigm(gv[1]) * cc + sigm(gv[0]) * tanhf_(gv[2]);
      const float hh = gv[3] * tanhf_(cc);   // no sigmoid on o-gate (ref)
      c_lds[lr_c][lc_c] = cc;

      const unsigned short mhi = f2bf(hh);
      const unsigned short mlo = f2bf(hh - bf2f(mhi));
      const unsigned ohi = (unsigned)__shfl_down((int)(unsigned)mhi, 1, 64);
      const unsigned olo = (unsigned)__shfl_down((int)(unsigned)mlo, 1, 64);
      if ((tid & 1) == 0) {                  // lc_c even; neighbor = lc_c+1
        const int gidx = (row_base + lr_c) * HH + hcol_base + lc_c;
        const unsigned ph = (unsigned)mhi | (ohi << 16);
        const unsigned pl = (unsigned)mlo | (olo << 16);
        if (fast) {                          // write-through L1 -> XCD L2
          ((unsigned*)whi)[gidx >> 1] = ph;
          ((unsigned*)wlo)[gidx >> 1] = pl;
        } else {
          __hip_atomic_store((unsigned*)whi + (gidx >> 1), ph, __ATOMIC_RELAXED, __HIP_MEMORY_SCOPE_AGENT);
          __hip_atomic_store((unsigned*)wlo + (gidx >> 1), pl, __ATOMIC_RELAXED, __HIP_MEMORY_SCOPE_AGENT);
        }
      }
      if (tid < 16 && t + 1 < SS) {
        const int row = row_base + tid;
        x_lds[tid] = xin[(row >> 1) * (SS * 2) + (t + 1) * 2 + (row & 1)];
      }
    }
    gbar();
    cur = nxt;
  }

  // ---- output projection: final h in parity cur = 256%3 = 1 ----
  if (p == 0 && tid < 256) {
    const unsigned short* fhi = hbhi[cur];
    const unsigned short* flo = hblo[cur];
    const int rloc = tid >> 4, s = tid & 15;
    const int row = row_base + rloc;
    float sum = 0.0f;
#pragma unroll
    for (int i = 0; i < 12; ++i) {
      const int u = row * 192 + s * 12 + i;  // u64 idx; k0 = s*48 + i*4
      unsigned long long vh, vl;
      if (fast) {                            // fresh in this XCD's L2
        vh = *((const unsigned long long*)fhi + u);
        vl = *((const unsigned long long*)flo + u);
      } else {
        vh = __hip_atomic_load((unsigned long long*)fhi + u, __ATOMIC_RELAXED, __HIP_MEMORY_SCOPE_AGENT);
        vl = __hip_atomic_load((unsigned long long*)flo + u, __ATOMIC_RELAXED, __HIP_MEMORY_SCOPE_AGENT);
      }
#pragma unroll
      for (int j = 0; j < 4; ++j) {
        const float h = bf2f((unsigned short)(vh >> (16 * j))) +
                        bf2f((unsigned short)(vl >> (16 * j)));
        sum += h * Wout[s * 48 + i * 4 + j];
      }
    }
#pragma unroll
    for (int off = 8; off; off >>= 1) sum += __shfl_down(sum, off, 16);
    if (s == 0) out[row] = sum + bout[0];
  }
}

extern "C" void kernel_launch(void* const* d_in, const int* in_sizes, int n_in,
                              void* d_out, int out_size, void* d_ws, size_t ws_size,
                              hipStream_t stream) {
  const float* xin  = (const float*)d_in[0];
  const float* h0   = (const float*)d_in[1];
  const float* c0   = (const float*)d_in[2];
  const float* Wi   = (const float*)d_in[3];
  const float* bi   = (const float*)d_in[4];
  const float* Wf   = (const float*)d_in[5];
  const float* bfv  = (const float*)d_in[6];
  const float* Wc   = (const float*)d_in[7];
  const float* bc   = (const float*)d_in[8];
  const float* Wo   = (const float*)d_in[9];
  const float* bo   = (const float*)d_in[10];
  const float* Wout = (const float*)d_in[11];
  const float* bout = (const float*)d_in[12];
  float* out = (float*)d_out;

  char* ws = (char*)d_ws;
  const size_t HB = (size_t)NROW * HH * sizeof(unsigned short);  // 196608
  unsigned short* hhi0 = (unsigned short*)(ws);
  unsigned short* hhi1 = (unsigned short*)(ws + HB);
  unsigned short* hhi2 = (unsigned short*)(ws + 2 * HB);
  unsigned short* hlo0 = (unsigned short*)(ws + 3 * HB);
  unsigned short* hlo1 = (unsigned short*)(ws + 4 * HB);
  unsigned short* hlo2 = (unsigned short*)(ws + 5 * HB);
  unsigned*       bar  = (unsigned*)(ws + 6 * HB);

  hipMemsetAsync(bar, 0, 4096, stream);    // zero barrier/rendezvous counters

  (void)in_sizes; (void)n_in; (void)out_size; (void)ws_size;
  hipLaunchKernelGGL(lstm_persistent, dim3(GR * GP), dim3(512), 0, stream,
                     xin, h0, c0, Wi, bi, Wf, bfv, Wc, bc, Wo, bo,
                     Wout, bout, out, hhi0, hhi1, hhi2, hlo0, hlo1, hlo2, bar);
}